// Round 7
// baseline (753.446 us; speedup 1.0000x reference)
//
#include <hip/hip_runtime.h>
#include <hip/hip_bf16.h>

#define B_  4
#define T_  2048
#define D_  1024
#define H_  16
#define HD_ 64
#define M_  (B_*T_)   // 8192
#define CH_ 16        // scan chunk (steps per LDS buffer)

typedef __attribute__((ext_vector_type(4))) float f32x4;
typedef __attribute__((ext_vector_type(8))) short bf16x8;

__device__ __forceinline__ float sigmoidf_(float x){ return 1.0f/(1.0f+__expf(-x)); }
__device__ __forceinline__ float siluf_(float x){ return x/(1.0f+__expf(-x)); }

// f32 -> bf16 (RNE), raw ushort
__device__ __forceinline__ unsigned short f2bf(float f){
  unsigned int u = __float_as_uint(f);
  unsigned int r = (u + 0x7FFFu + ((u >> 16) & 1u)) >> 16;
  return (unsigned short)r;
}
__device__ __forceinline__ float bf2f(unsigned short u){
  return __uint_as_float(((unsigned int)u) << 16);
}

// async global->LDS, 16 bytes per lane (dest = wave-uniform base + lane*16)
__device__ __forceinline__ void gload16(const void* g, void* l){
  using GP = const __attribute__((address_space(1))) unsigned int*;
  using LP = __attribute__((address_space(3))) unsigned int*;
  __builtin_amdgcn_global_load_lds(
      reinterpret_cast<GP>(reinterpret_cast<unsigned long long>(g)),
      reinterpret_cast<LP>(reinterpret_cast<unsigned long long>(l)),
      16, 0, 0);
}
// async global->LDS, 4 bytes per lane
__device__ __forceinline__ void gload4(const void* g, void* l){
  using GP = const __attribute__((address_space(1))) unsigned int*;
  using LP = __attribute__((address_space(3))) unsigned int*;
  __builtin_amdgcn_global_load_lds(
      reinterpret_cast<GP>(reinterpret_cast<unsigned long long>(g)),
      reinterpret_cast<LP>(reinterpret_cast<unsigned long long>(l)),
      4, 0, 0);
}

// DPP butterfly add stage (VALU, no DS pipe)
template<int CTRL>
__device__ __forceinline__ float dpp_add(float x){
  int y = __builtin_amdgcn_update_dpp(0, __float_as_int(x), CTRL, 0xF, 0xF, true);
  return x + __int_as_float(y);
}
// reduce over 16-lane rows (kseg = lane&15): xor1, xor2, then half/full mirror
// (mirrors are exact xor4/xor8 equivalents once 4-/8-groups are uniform)
__device__ __forceinline__ float row_reduce16(float x){
  x = dpp_add<0xB1>(x);    // quad_perm xor1
  x = dpp_add<0x4E>(x);    // quad_perm xor2
  x = dpp_add<0x141>(x);   // ROW_HALF_MIRROR (== xor4)
  x = dpp_add<0x140>(x);   // ROW_MIRROR      (== xor8)
  return x;
}

// unpack 4 bf16 (uint2) -> f32x4
__device__ __forceinline__ f32x4 unpack4(uint2 d){
  f32x4 r;
  r[0] = __uint_as_float(d.x << 16);
  r[1] = __uint_as_float(d.x & 0xffff0000u);
  r[2] = __uint_as_float(d.y << 16);
  r[3] = __uint_as_float(d.y & 0xffff0000u);
  return r;
}

// ---------------- converts ----------------
__global__ __launch_bounds__(256) void k_f32_to_bf16(const float* __restrict__ src,
                                                     unsigned short* __restrict__ dst, int n){
  int i = (blockIdx.x * 256 + threadIdx.x) * 4;
  if (i >= n) return;
  float4 v = *reinterpret_cast<const float4*>(src + i);
  ushort4 o;
  o.x = f2bf(v.x); o.y = f2bf(v.y); o.z = f2bf(v.z); o.w = f2bf(v.w);
  *reinterpret_cast<ushort4*>(dst + i) = o;
}

// dst[Nd][K] bf16 = transpose(src[K][Ns]); rows Ns..Nd zero-padded
__global__ void k_transpose_bf16(const float* __restrict__ src, unsigned short* __restrict__ dst,
                                 int K, int Ns, int Nd){
  __shared__ float tile[32][33];
  int k0 = blockIdx.x * 32, n0 = blockIdx.y * 32;
  int lx = threadIdx.x, ly = threadIdx.y;           // 32 x 8
  for (int i = ly; i < 32; i += 8){
    int n = n0 + lx;
    tile[i][lx] = (n < Ns) ? src[(size_t)(k0 + i) * Ns + n] : 0.0f;
  }
  __syncthreads();
  for (int i = ly; i < 32; i += 8){
    int n = n0 + i;
    if (n < Nd) dst[(size_t)n * K + k0 + lx] = f2bf(tile[lx][i]);
  }
}

// ---------------- bf16 MFMA GEMM: C[M,N] = A[M,K(lda)] * BT[N,K]^T ----------------
// 128x128 tile, BK=32, 4 waves (2x2), 16x16x32 MFMA, global_load_lds + XOR swizzle.
// EPI: 0 = f32 store, 1 = bf16, 2 = silu->bf16, 3 = sigmoid->bf16,
//      4 = silu + per-64col-head l2norm -> bf16, 5 = bf16 + gamma side-channel (cols<16)
template<int EPI>
__global__ __launch_bounds__(256) void k_gemm(const unsigned short* __restrict__ A,
                                              const unsigned short* __restrict__ BT,
                                              void* __restrict__ Cout,
                                              int K, int lda, int ldc,
                                              float* __restrict__ extra){
  __shared__ __align__(16) unsigned short As[128*32];
  __shared__ __align__(16) unsigned short Bs[128*32];
  const int tid = threadIdx.x;
  const int l = tid & 63, w = tid >> 6;
  const int wm = w >> 1, wn = w & 1;
  const int m0 = blockIdx.y * 128, n0 = blockIdx.x * 128;
  const int lr = l & 15, kg = l >> 4;

  f32x4 acc[4][4];
#pragma unroll
  for (int i = 0; i < 4; ++i)
#pragma unroll
    for (int j = 0; j < 4; ++j) acc[i][j] = 0.0f;

  for (int kt = 0; kt < K; kt += 32){
    __syncthreads();
    {
      int ch = tid;
      int row = ch >> 2;
      int sw  = (row & 3) ^ ((row >> 2) & 3);
      int cc  = (ch & 3) ^ sw;
      gload16(A  + (size_t)(m0 + row) * lda + kt + cc * 8, (char*)As + ch * 16);
      gload16(BT + (size_t)(n0 + row) * K   + kt + cc * 8, (char*)Bs + ch * 16);
      ch = tid + 256;
      row = ch >> 2;
      sw  = (row & 3) ^ ((row >> 2) & 3);
      cc  = (ch & 3) ^ sw;
      gload16(A  + (size_t)(m0 + row) * lda + kt + cc * 8, (char*)As + ch * 16);
      gload16(BT + (size_t)(n0 + row) * K   + kt + cc * 8, (char*)Bs + ch * 16);
    }
    __syncthreads();

    bf16x8 af[4], bfr[4];
#pragma unroll
    for (int mi = 0; mi < 4; ++mi){
      int row = wm*64 + mi*16 + lr;
      int sw  = (row & 3) ^ ((row >> 2) & 3);
      af[mi]  = *reinterpret_cast<const bf16x8*>((const char*)As + row*64 + ((kg ^ sw) * 16));
    }
#pragma unroll
    for (int ni = 0; ni < 4; ++ni){
      int col = wn*64 + ni*16 + lr;
      int sw  = (col & 3) ^ ((col >> 2) & 3);
      bfr[ni] = *reinterpret_cast<const bf16x8*>((const char*)Bs + col*64 + ((kg ^ sw) * 16));
    }
#pragma unroll
    for (int mi = 0; mi < 4; ++mi)
#pragma unroll
      for (int ni = 0; ni < 4; ++ni)
        acc[mi][ni] = __builtin_amdgcn_mfma_f32_16x16x32_bf16(af[mi], bfr[ni], acc[mi][ni], 0, 0, 0);
  }

#pragma unroll
  for (int mi = 0; mi < 4; ++mi){
    if (EPI == 4){
      // silu then l2-normalize each row over this wave's 64-col head block
#pragma unroll
      for (int r = 0; r < 4; ++r){
        float vals[4]; float ss = 0.0f;
#pragma unroll
        for (int ni = 0; ni < 4; ++ni){ vals[ni] = siluf_(acc[mi][ni][r]); ss += vals[ni]*vals[ni]; }
        ss += __shfl_xor(ss, 1); ss += __shfl_xor(ss, 2);
        ss += __shfl_xor(ss, 4); ss += __shfl_xor(ss, 8);
        const float inv = 1.0f / fmaxf(sqrtf(ss), 1e-12f);
        const int row = m0 + wm*64 + mi*16 + kg*4 + r;
#pragma unroll
        for (int ni = 0; ni < 4; ++ni){
          const int col = n0 + wn*64 + ni*16 + lr;
          ((unsigned short*)Cout)[(size_t)row*ldc + col] = f2bf(vals[ni]*inv);
        }
      }
    } else {
#pragma unroll
      for (int ni = 0; ni < 4; ++ni)
#pragma unroll
        for (int r = 0; r < 4; ++r){
          const int row = m0 + wm*64 + mi*16 + kg*4 + r;
          const int col = n0 + wn*64 + ni*16 + lr;
          const float v = acc[mi][ni][r];
          if (EPI == 0){
            ((float*)Cout)[(size_t)row*ldc + col] = v;
          } else {
            float ov = v;
            if (EPI == 2) ov = siluf_(v);
            if (EPI == 3) ov = sigmoidf_(v);
            ((unsigned short*)Cout)[(size_t)row*ldc + col] = f2bf(ov);
            if (EPI == 5 && col < 16)
              extra[((size_t)(row >> 11) * 16 + col) * 2048 + (row & 2047)] = -sigmoidf_(v);
          }
        }
    }
  }
}

// ---------------- sequential DPLR scan ----------------
// grid: 1024 blocks; bh = blk&63, vg = blk>>6 (16 v-groups of 4 columns).
// 64 threads (one wave). lane: kseg = l&15 (4 k-elems each), c = l>>4 (column).
// S[k][col]: 1x f32x4 per lane. All cross-lane reduction via DPP (VALU pipe).
// Chunk-level register preload: all 16 steps' q/k/e/v/g batch-read from LDS
// into registers (static offsets), one lgkmcnt wait, then pure-VALU steps.
__global__ __launch_bounds__(64) void k_scan(const unsigned short* __restrict__ qs,
                                             const unsigned short* __restrict__ ks,
                                             const unsigned short* __restrict__ vb,
                                             const unsigned short* __restrict__ eb,
                                             const float* __restrict__ gammac,
                                             unsigned short* __restrict__ o){
  __shared__ __align__(16) unsigned short qS[2][CH_*64];
  __shared__ __align__(16) unsigned short kS[2][CH_*64];
  __shared__ __align__(16) unsigned short eS[2][CH_*64];
  __shared__ __align__(16) unsigned short vS[2][CH_*4];
  __shared__ __align__(16) float          gS[2][CH_];

  const int bh = blockIdx.x & 63, vg = blockIdx.x >> 6;
  const int l = threadIdx.x;
  const int kseg = l & 15, c = l >> 4;
  const int b = bh >> 4, h = bh & 15;
  const int bT = b * T_;
  const int hc = h * HD_;
  const float* gb = gammac + (size_t)bh * T_;

  f32x4 S = 0.0f;

  auto stage = [&](int nb, int chk){
    const int t0 = chk * CH_;
#pragma unroll
    for (int i = 0; i < 2; ++i){
      const size_t src = (size_t)(bT + t0 + i*8 + (l>>3)) * D_ + hc + (l&7)*8;
      gload16(qs + src, (char*)&qS[nb][0] + i*1024 + l*16);
      gload16(ks + src, (char*)&kS[nb][0] + i*1024 + l*16);
      gload16(eb + src, (char*)&eS[nb][0] + i*1024 + l*16);
    }
    if (l < 32)
      gload4(vb + (size_t)(bT + t0 + (l>>1)) * D_ + hc + vg*4 + (l&1)*2,
             (char*)&vS[nb][0] + l*4);
    if (l < 4)
      gload16(gb + t0 + l*4, (char*)&gS[nb][0] + l*16);
  };

  stage(0, 0);
  asm volatile("s_waitcnt vmcnt(0)" ::: "memory");
  __builtin_amdgcn_sched_barrier(0);

  unsigned short* ob = o + (size_t)bT * D_ + hc + vg*4 + c;

  for (int chk = 0; chk < T_/CH_; ++chk){
    const int cur = chk & 1;
    if (chk + 1 < T_/CH_) stage(cur ^ 1, chk + 1);

    // ---- chunk preload: LDS -> registers (all static offsets) ----
    const char* qB = (const char*)&qS[cur][0];
    const char* kB = (const char*)&kS[cur][0];
    const char* eB = (const char*)&eS[cur][0];
    uint2 rq[CH_], rk[CH_], re[CH_];
    unsigned short rv[CH_];
    f32x4 rg[CH_/4];
#pragma unroll
    for (int s = 0; s < CH_; ++s){
      rq[s] = *(const uint2*)(qB + s*128 + kseg*8);
      rk[s] = *(const uint2*)(kB + s*128 + kseg*8);
      re[s] = *(const uint2*)(eB + s*128 + kseg*8);
      rv[s] = vS[cur][s*4 + c];
    }
#pragma unroll
    for (int i = 0; i < CH_/4; ++i)
      rg[i] = *(const f32x4*)&gS[cur][i*4];
    asm volatile("s_waitcnt lgkmcnt(0)" ::: "memory");
    __builtin_amdgcn_sched_barrier(0);

    // ---- 16 pure-register steps ----
#pragma unroll
    for (int s = 0; s < CH_; ++s){
      f32x4 E = unpack4(re[s]);
      f32x4 K = unpack4(rk[s]);
      f32x4 Q = unpack4(rq[s]);
      const float gsc = rg[s>>2][s&3];
      S *= E;                                   // decay
      f32x4 sv = (K * E) * S;                   // (k*ef) ⊙ S'
      float red = (sv[0]+sv[1]) + (sv[2]+sv[3]);
      red = row_reduce16(red);                  // sum over k (DPP butterfly)
      float tv = fmaf(gsc, red, bf2f(rv[s]));   // gamma*sab + v
      S += K * tv;                              // S += k (sab+v)
      f32x4 ov = Q * S;
      float out = (ov[0]+ov[1]) + (ov[2]+ov[3]);
      out = row_reduce16(out);                  // sum over k (DPP butterfly)
      if (kseg == 0) ob[(size_t)(chk*CH_ + s) * D_] = f2bf(out);
    }
    asm volatile("s_waitcnt vmcnt(0)" ::: "memory");
    __builtin_amdgcn_sched_barrier(0);
  }
}

// ---------------- output gate (pre-sigmoided) + layernorm -> bf16 ----------------
__global__ __launch_bounds__(256) void k_gate_ln(const unsigned short* __restrict__ o,
                                                 const unsigned short* __restrict__ ogs,
                                                 const float* __restrict__ nw,
                                                 unsigned short* __restrict__ onb){
  const int tok = blockIdx.x;
  const int tid = threadIdx.x;
  const size_t base = (size_t)tok * D_ + tid * 4;
  ushort4 o4 = *(const ushort4*)(o + base);
  ushort4 g4 = *(const ushort4*)(ogs + base);
  float ov[4] = { bf2f(o4.x), bf2f(o4.y), bf2f(o4.z), bf2f(o4.w) };
  ov[0] *= bf2f(g4.x); ov[1] *= bf2f(g4.y);
  ov[2] *= bf2f(g4.z); ov[3] *= bf2f(g4.w);
  float s1 = ov[0] + ov[1] + ov[2] + ov[3];
  float s2 = ov[0]*ov[0] + ov[1]*ov[1] + ov[2]*ov[2] + ov[3]*ov[3];
#pragma unroll
  for (int off = 1; off < 64; off <<= 1){ s1 += __shfl_xor(s1, off); s2 += __shfl_xor(s2, off); }
  __shared__ float w1[4], w2[4];
  const int w = tid >> 6;
  if ((tid & 63) == 0){ w1[w] = s1; w2[w] = s2; }
  __syncthreads();
  s1 = w1[0] + w1[1] + w1[2] + w1[3];
  s2 = w2[0] + w2[1] + w2[2] + w2[3];
  const float mu  = s1 * (1.0f/1024.0f);
  const float var = s2 * (1.0f/1024.0f) - mu*mu;
  const float rs  = rsqrtf(var + 1e-5f);
  const float4 n4 = *(const float4*)(nw + tid * 4);
  ushort4 ou;
  ou.x = f2bf((ov[0] - mu) * rs * n4.x);
  ou.y = f2bf((ov[1] - mu) * rs * n4.y);
  ou.z = f2bf((ov[2] - mu) * rs * n4.z);
  ou.w = f2bf((ov[3] - mu) * rs * n4.w);
  *(ushort4*)(onb + base) = ou;
}

// ---------------- launcher ----------------
extern "C" void kernel_launch(void* const* d_in, const int* in_sizes, int n_in,
                              void* d_out, int out_size, void* d_ws, size_t ws_size,
                              hipStream_t stream){
  const float* x    = (const float*)d_in[0];
  const float* Wq   = (const float*)d_in[1];
  const float* Wk   = (const float*)d_in[2];
  const float* Wv   = (const float*)d_in[3];
  const float* Wg   = (const float*)d_in[4];
  const float* Wf1  = (const float*)d_in[5];
  const float* Wf2  = (const float*)d_in[6];
  const float* Wog1 = (const float*)d_in[7];
  const float* Wog2 = (const float*)d_in[8];
  const float* nw   = (const float*)d_in[9];
  const float* Wo   = (const float*)d_in[10];

  // workspace budget check (bail cleanly instead of faulting)
  if (ws_size < 97779712ull) return;

  char* base = (char*)d_ws;
  size_t off = 0;
  auto alloc = [&](size_t bytes)->char*{
    char* r = base + off; off += (bytes + 255) & ~(size_t)255; return r;
  };
  unsigned short* xb    = (unsigned short*)alloc((size_t)M_*D_*2);      // 16MB (scan out reuses)
  unsigned short* WqT   = (unsigned short*)alloc((size_t)D_*D_*2);      // 2MB
  unsigned short* WkT   = (unsigned short*)alloc((size_t)D_*D_*2);
  unsigned short* WvT   = (unsigned short*)alloc((size_t)D_*D_*2);
  unsigned short* WoT   = (unsigned short*)alloc((size_t)D_*D_*2);
  unsigned short* WgfoT = (unsigned short*)alloc((size_t)256*D_*2);     // 0.5MB
  unsigned short* Wf2T  = (unsigned short*)alloc((size_t)D_*64*2);      // 128KB
  unsigned short* Wog2T = (unsigned short*)alloc((size_t)D_*64*2);
  unsigned short* qb    = (unsigned short*)alloc((size_t)M_*D_*2);      // 16MB (og-sig reuses)
  unsigned short* kb    = (unsigned short*)alloc((size_t)M_*D_*2);      // 16MB (LN out reuses)
  unsigned short* vb    = (unsigned short*)alloc((size_t)M_*D_*2);      // 16MB
  unsigned short* gfo   = (unsigned short*)alloc((size_t)M_*256*2);     // 4MB
  unsigned short* efb   = (unsigned short*)alloc((size_t)M_*D_*2);      // 16MB
  float*          gammac= (float*)alloc((size_t)64*T_*4);               // 0.5MB
  // aliases (strictly ordered reuse):
  unsigned short* obuf = xb;   // xb dead after level-1 GEMMs; scan writes here
  unsigned short* ogs  = qb;   // qb dead after scan; og-sigmoid GEMM writes here
  unsigned short* onb  = kb;   // kb dead after scan; gate_ln writes here

  dim3 blkT(32, 8);

  // converts / transposes
  k_f32_to_bf16<<<8192, 256, 0, stream>>>(x, xb, M_*D_);
  k_transpose_bf16<<<dim3(32,32), blkT, 0, stream>>>(Wq,   WqT,  1024, 1024, 1024);
  k_transpose_bf16<<<dim3(32,32), blkT, 0, stream>>>(Wk,   WkT,  1024, 1024, 1024);
  k_transpose_bf16<<<dim3(32,32), blkT, 0, stream>>>(Wv,   WvT,  1024, 1024, 1024);
  k_transpose_bf16<<<dim3(32,32), blkT, 0, stream>>>(Wo,   WoT,  1024, 1024, 1024);
  // fused bottleneck weights: rows 0-15 Wg^T, 16-79 Wf1^T, 80-143 Wog1^T, 144-255 zero
  k_transpose_bf16<<<dim3(32,1),  blkT, 0, stream>>>(Wg,   WgfoT,            1024, 16,  16);
  k_transpose_bf16<<<dim3(32,2),  blkT, 0, stream>>>(Wf1,  WgfoT + 16*1024,  1024, 64,  64);
  k_transpose_bf16<<<dim3(32,6),  blkT, 0, stream>>>(Wog1, WgfoT + 80*1024,  1024, 64, 176);
  k_transpose_bf16<<<dim3(2,32),  blkT, 0, stream>>>(Wf2,  Wf2T,  64, 1024, 1024);
  k_transpose_bf16<<<dim3(2,32),  blkT, 0, stream>>>(Wog2, Wog2T, 64, 1024, 1024);

  // level-1 projections with fused activations
  k_gemm<2><<<dim3(8,64), 256, 0, stream>>>(xb, WqT,   qb,  1024, 1024, 1024, nullptr); // silu
  k_gemm<4><<<dim3(8,64), 256, 0, stream>>>(xb, WkT,   kb,  1024, 1024, 1024, nullptr); // silu+l2norm
  k_gemm<1><<<dim3(8,64), 256, 0, stream>>>(xb, WvT,   vb,  1024, 1024, 1024, nullptr); // plain
  k_gemm<5><<<dim3(2,64), 256, 0, stream>>>(xb, WgfoT, gfo, 1024, 1024, 256,  gammac); // + gamma
  // level-2 bottleneck GEMM: ef = sigmoid(fmid @ Wf2)
  k_gemm<3><<<dim3(8,64), 256, 0, stream>>>(gfo + 16, Wf2T, efb, 64, 256, 1024, nullptr);

  // sequential recurrence (writes obuf = xb)
  k_scan<<<1024, 64, 0, stream>>>(qb, kb, vb, efb, gammac, obuf);

  // og gate: sigmoid(ogmid @ Wog2) -> ogs (= qb, dead after scan)
  k_gemm<3><<<dim3(8,64), 256, 0, stream>>>(gfo + 80, Wog2T, ogs, 64, 256, 1024, nullptr);

  // gate + layernorm (writes onb = kb)
  k_gate_ln<<<8192, 256, 0, stream>>>(obuf, ogs, nw, onb);

  // final projection -> d_out (fp32)
  k_gemm<0><<<dim3(8,64), 256, 0, stream>>>(onb, WoT, (float*)d_out, 1024, 1024, 1024, nullptr);
}

// Round 8
// 753.220 us; speedup vs baseline: 1.0003x; 1.0003x over previous
//
#include <hip/hip_runtime.h>
#include <hip/hip_bf16.h>

#define B_  4
#define T_  2048
#define D_  1024
#define H_  16
#define HD_ 64
#define M_  (B_*T_)   // 8192
#define CH_ 16        // scan chunk (steps per LDS buffer)

typedef __attribute__((ext_vector_type(4))) float f32x4;
typedef __attribute__((ext_vector_type(8))) short bf16x8;

__device__ __forceinline__ float sigmoidf_(float x){ return 1.0f/(1.0f+__expf(-x)); }
__device__ __forceinline__ float siluf_(float x){ return x/(1.0f+__expf(-x)); }

// f32 -> bf16 (RNE), raw ushort
__device__ __forceinline__ unsigned short f2bf(float f){
  unsigned int u = __float_as_uint(f);
  unsigned int r = (u + 0x7FFFu + ((u >> 16) & 1u)) >> 16;
  return (unsigned short)r;
}
__device__ __forceinline__ float bf2f(unsigned short u){
  return __uint_as_float(((unsigned int)u) << 16);
}

// async global->LDS, 16 bytes per lane (dest = wave-uniform base + lane*16)
__device__ __forceinline__ void gload16(const void* g, void* l){
  using GP = const __attribute__((address_space(1))) unsigned int*;
  using LP = __attribute__((address_space(3))) unsigned int*;
  __builtin_amdgcn_global_load_lds(
      reinterpret_cast<GP>(reinterpret_cast<unsigned long long>(g)),
      reinterpret_cast<LP>(reinterpret_cast<unsigned long long>(l)),
      16, 0, 0);
}
// async global->LDS, 4 bytes per lane
__device__ __forceinline__ void gload4(const void* g, void* l){
  using GP = const __attribute__((address_space(1))) unsigned int*;
  using LP = __attribute__((address_space(3))) unsigned int*;
  __builtin_amdgcn_global_load_lds(
      reinterpret_cast<GP>(reinterpret_cast<unsigned long long>(g)),
      reinterpret_cast<LP>(reinterpret_cast<unsigned long long>(l)),
      4, 0, 0);
}

// DPP butterfly add stage (VALU, no DS pipe)
template<int CTRL>
__device__ __forceinline__ float dpp_add(float x){
  int y = __builtin_amdgcn_update_dpp(0, __float_as_int(x), CTRL, 0xF, 0xF, true);
  return x + __int_as_float(y);
}
// reduce over 16-lane rows (kseg = lane&15): xor1, xor2, then half/full mirror
// (mirrors are exact xor4/xor8 equivalents once 4-/8-groups are uniform)
__device__ __forceinline__ float row_reduce16(float x){
  x = dpp_add<0xB1>(x);    // quad_perm xor1
  x = dpp_add<0x4E>(x);    // quad_perm xor2
  x = dpp_add<0x141>(x);   // ROW_HALF_MIRROR (== xor4)
  x = dpp_add<0x140>(x);   // ROW_MIRROR      (== xor8)
  return x;
}

// unpack 4 bf16 (uint2) -> f32x4
__device__ __forceinline__ f32x4 unpack4(uint2 d){
  f32x4 r;
  r[0] = __uint_as_float(d.x << 16);
  r[1] = __uint_as_float(d.x & 0xffff0000u);
  r[2] = __uint_as_float(d.y << 16);
  r[3] = __uint_as_float(d.y & 0xffff0000u);
  return r;
}

// ---------------- converts ----------------
__global__ __launch_bounds__(256) void k_f32_to_bf16(const float* __restrict__ src,
                                                     unsigned short* __restrict__ dst, int n){
  int i = (blockIdx.x * 256 + threadIdx.x) * 4;
  if (i >= n) return;
  float4 v = *reinterpret_cast<const float4*>(src + i);
  ushort4 o;
  o.x = f2bf(v.x); o.y = f2bf(v.y); o.z = f2bf(v.z); o.w = f2bf(v.w);
  *reinterpret_cast<ushort4*>(dst + i) = o;
}

// dst[Nd][K] bf16 = transpose(src[K][Ns]); rows Ns..Nd zero-padded
__global__ void k_transpose_bf16(const float* __restrict__ src, unsigned short* __restrict__ dst,
                                 int K, int Ns, int Nd){
  __shared__ float tile[32][33];
  int k0 = blockIdx.x * 32, n0 = blockIdx.y * 32;
  int lx = threadIdx.x, ly = threadIdx.y;           // 32 x 8
  for (int i = ly; i < 32; i += 8){
    int n = n0 + lx;
    tile[i][lx] = (n < Ns) ? src[(size_t)(k0 + i) * Ns + n] : 0.0f;
  }
  __syncthreads();
  for (int i = ly; i < 32; i += 8){
    int n = n0 + i;
    if (n < Nd) dst[(size_t)n * K + k0 + lx] = f2bf(tile[lx][i]);
  }
}

// ---------------- bf16 MFMA GEMM: C[M,N] = A[M,K(lda)] * BT[N,K]^T ----------------
// 128x128 tile, BK=32, 4 waves (2x2), 16x16x32 MFMA, global_load_lds + XOR swizzle.
// EPI: 0 = f32 store, 1 = bf16, 2 = silu->bf16, 3 = sigmoid->bf16,
//      4 = silu + per-64col-head l2norm -> bf16, 5 = bf16 + gamma side-channel (cols<16)
template<int EPI>
__global__ __launch_bounds__(256) void k_gemm(const unsigned short* __restrict__ A,
                                              const unsigned short* __restrict__ BT,
                                              void* __restrict__ Cout,
                                              int K, int lda, int ldc,
                                              float* __restrict__ extra){
  __shared__ __align__(16) unsigned short As[128*32];
  __shared__ __align__(16) unsigned short Bs[128*32];
  const int tid = threadIdx.x;
  const int l = tid & 63, w = tid >> 6;
  const int wm = w >> 1, wn = w & 1;
  const int m0 = blockIdx.y * 128, n0 = blockIdx.x * 128;
  const int lr = l & 15, kg = l >> 4;

  f32x4 acc[4][4];
#pragma unroll
  for (int i = 0; i < 4; ++i)
#pragma unroll
    for (int j = 0; j < 4; ++j) acc[i][j] = 0.0f;

  for (int kt = 0; kt < K; kt += 32){
    __syncthreads();
    {
      int ch = tid;
      int row = ch >> 2;
      int sw  = (row & 3) ^ ((row >> 2) & 3);
      int cc  = (ch & 3) ^ sw;
      gload16(A  + (size_t)(m0 + row) * lda + kt + cc * 8, (char*)As + ch * 16);
      gload16(BT + (size_t)(n0 + row) * K   + kt + cc * 8, (char*)Bs + ch * 16);
      ch = tid + 256;
      row = ch >> 2;
      sw  = (row & 3) ^ ((row >> 2) & 3);
      cc  = (ch & 3) ^ sw;
      gload16(A  + (size_t)(m0 + row) * lda + kt + cc * 8, (char*)As + ch * 16);
      gload16(BT + (size_t)(n0 + row) * K   + kt + cc * 8, (char*)Bs + ch * 16);
    }
    __syncthreads();

    bf16x8 af[4], bfr[4];
#pragma unroll
    for (int mi = 0; mi < 4; ++mi){
      int row = wm*64 + mi*16 + lr;
      int sw  = (row & 3) ^ ((row >> 2) & 3);
      af[mi]  = *reinterpret_cast<const bf16x8*>((const char*)As + row*64 + ((kg ^ sw) * 16));
    }
#pragma unroll
    for (int ni = 0; ni < 4; ++ni){
      int col = wn*64 + ni*16 + lr;
      int sw  = (col & 3) ^ ((col >> 2) & 3);
      bfr[ni] = *reinterpret_cast<const bf16x8*>((const char*)Bs + col*64 + ((kg ^ sw) * 16));
    }
#pragma unroll
    for (int mi = 0; mi < 4; ++mi)
#pragma unroll
      for (int ni = 0; ni < 4; ++ni)
        acc[mi][ni] = __builtin_amdgcn_mfma_f32_16x16x32_bf16(af[mi], bfr[ni], acc[mi][ni], 0, 0, 0);
  }

#pragma unroll
  for (int mi = 0; mi < 4; ++mi){
    if (EPI == 4){
      // silu then l2-normalize each row over this wave's 64-col head block
#pragma unroll
      for (int r = 0; r < 4; ++r){
        float vals[4]; float ss = 0.0f;
#pragma unroll
        for (int ni = 0; ni < 4; ++ni){ vals[ni] = siluf_(acc[mi][ni][r]); ss += vals[ni]*vals[ni]; }
        ss += __shfl_xor(ss, 1); ss += __shfl_xor(ss, 2);
        ss += __shfl_xor(ss, 4); ss += __shfl_xor(ss, 8);
        const float inv = 1.0f / fmaxf(sqrtf(ss), 1e-12f);
        const int row = m0 + wm*64 + mi*16 + kg*4 + r;
#pragma unroll
        for (int ni = 0; ni < 4; ++ni){
          const int col = n0 + wn*64 + ni*16 + lr;
          ((unsigned short*)Cout)[(size_t)row*ldc + col] = f2bf(vals[ni]*inv);
        }
      }
    } else {
#pragma unroll
      for (int ni = 0; ni < 4; ++ni)
#pragma unroll
        for (int r = 0; r < 4; ++r){
          const int row = m0 + wm*64 + mi*16 + kg*4 + r;
          const int col = n0 + wn*64 + ni*16 + lr;
          const float v = acc[mi][ni][r];
          if (EPI == 0){
            ((float*)Cout)[(size_t)row*ldc + col] = v;
          } else {
            float ov = v;
            if (EPI == 2) ov = siluf_(v);
            if (EPI == 3) ov = sigmoidf_(v);
            ((unsigned short*)Cout)[(size_t)row*ldc + col] = f2bf(ov);
            if (EPI == 5 && col < 16)
              extra[((size_t)(row >> 11) * 16 + col) * 2048 + (row & 2047)] = -sigmoidf_(v);
          }
        }
    }
  }
}

// ---------------- sequential DPLR scan ----------------
// grid: 1024 blocks; bh = blk&63, vg = blk>>6 (16 v-groups of 4 columns).
// 64 threads (one wave). lane: kseg = l&15 (4 k-elems each), c = l>>4 (column).
// Chain-shortened step: sab = (K*E*E)^T S_old (KE2 off-chain); S = E*S_old + K*tv
// with E*S_old computed off-chain in parallel with the DPP reduction.
// 3-slot register pipeline: LDS loads for step s+2 issued during step s
// (small footprint so the compiler can keep it in VGPRs, unlike a 16-deep preload).
__global__ __launch_bounds__(64) void k_scan(const unsigned short* __restrict__ qs,
                                             const unsigned short* __restrict__ ks,
                                             const unsigned short* __restrict__ vb,
                                             const unsigned short* __restrict__ eb,
                                             const float* __restrict__ gammac,
                                             unsigned short* __restrict__ o){
  __shared__ __align__(16) unsigned short qS[2][CH_*64];
  __shared__ __align__(16) unsigned short kS[2][CH_*64];
  __shared__ __align__(16) unsigned short eS[2][CH_*64];
  __shared__ __align__(16) unsigned short vS[2][CH_*4];
  __shared__ __align__(16) float          gS[2][CH_];

  const int bh = blockIdx.x & 63, vg = blockIdx.x >> 6;
  const int l = threadIdx.x;
  const int kseg = l & 15, c = l >> 4;
  const int b = bh >> 4, h = bh & 15;
  const int bT = b * T_;
  const int hc = h * HD_;
  const float* gb = gammac + (size_t)bh * T_;

  f32x4 S = 0.0f;

  auto stage = [&](int nb, int chk){
    const int t0 = chk * CH_;
#pragma unroll
    for (int i = 0; i < 2; ++i){
      const size_t src = (size_t)(bT + t0 + i*8 + (l>>3)) * D_ + hc + (l&7)*8;
      gload16(qs + src, (char*)&qS[nb][0] + i*1024 + l*16);
      gload16(ks + src, (char*)&kS[nb][0] + i*1024 + l*16);
      gload16(eb + src, (char*)&eS[nb][0] + i*1024 + l*16);
    }
    if (l < 32)
      gload4(vb + (size_t)(bT + t0 + (l>>1)) * D_ + hc + vg*4 + (l&1)*2,
             (char*)&vS[nb][0] + l*4);
    if (l < 4)
      gload16(gb + t0 + l*4, (char*)&gS[nb][0] + l*16);
  };

  stage(0, 0);
  asm volatile("s_waitcnt vmcnt(0)" ::: "memory");
  __builtin_amdgcn_sched_barrier(0);

  unsigned short* ob = o + (size_t)bT * D_ + hc + vg*4 + c;

  for (int chk = 0; chk < T_/CH_; ++chk){
    const int cur = chk & 1;
    if (chk + 1 < T_/CH_) stage(cur ^ 1, chk + 1);  // 8 VMEM ops into other buffer

    const char* qB = (const char*)&qS[cur][0];
    const char* kB = (const char*)&kS[cur][0];
    const char* eB = (const char*)&eS[cur][0];

    // 3-slot rotating register pipeline (all indices static after unroll)
    uint2 pq[3], pk[3], pe[3];
    float pvf[3], pg[3];
    auto LD = [&](int s, int i){
      pq[i] = *(const uint2*)(qB + s*128 + kseg*8);
      pk[i] = *(const uint2*)(kB + s*128 + kseg*8);
      pe[i] = *(const uint2*)(eB + s*128 + kseg*8);
      pvf[i] = bf2f(vS[cur][s*4 + c]);
      pg[i] = gS[cur][s];
    };
    LD(0, 0); LD(1, 1);

#pragma unroll
    for (int s = 0; s < CH_; ++s){
      if (s + 2 < CH_) LD(s + 2, (s + 2) % 3);   // loads 2 steps ahead
      const int i = s % 3;
      f32x4 E = unpack4(pe[i]);
      f32x4 K = unpack4(pk[i]);
      f32x4 Q = unpack4(pq[i]);
      f32x4 KE2 = (K * E) * E;          // off-chain (independent of S)
      f32x4 sv  = KE2 * S;              // chain: uses S_old directly
      f32x4 ES  = E * S;                // off-chain decay, overlaps reduction
      float red = (sv[0]+sv[1]) + (sv[2]+sv[3]);
      red = row_reduce16(red);          // 4 DPP adds (VALU)
      float tv = fmaf(pg[i], red, pvf[i]);   // gamma*sab + v
      f32x4 Ktv = K * tv;
      S = ES + Ktv;                     // single add closes the chain
      f32x4 ov = Q * S;
      float out = (ov[0]+ov[1]) + (ov[2]+ov[3]);
      out = row_reduce16(out);          // off S-chain
      if (kseg == 0) ob[(size_t)(chk*CH_ + s) * D_] = f2bf(out);
    }
    // wait staging only (8 oldest VMEM ops), NOT this chunk's <=16 output stores:
    // vmcnt retires in order, so <=16 outstanding ==> all staging retired.
    asm volatile("s_waitcnt vmcnt(16)" ::: "memory");
    __builtin_amdgcn_sched_barrier(0);
  }
}

// ---------------- output gate (pre-sigmoided) + layernorm -> bf16 ----------------
__global__ __launch_bounds__(256) void k_gate_ln(const unsigned short* __restrict__ o,
                                                 const unsigned short* __restrict__ ogs,
                                                 const float* __restrict__ nw,
                                                 unsigned short* __restrict__ onb){
  const int tok = blockIdx.x;
  const int tid = threadIdx.x;
  const size_t base = (size_t)tok * D_ + tid * 4;
  ushort4 o4 = *(const ushort4*)(o + base);
  ushort4 g4 = *(const ushort4*)(ogs + base);
  float ov[4] = { bf2f(o4.x), bf2f(o4.y), bf2f(o4.z), bf2f(o4.w) };
  ov[0] *= bf2f(g4.x); ov[1] *= bf2f(g4.y);
  ov[2] *= bf2f(g4.z); ov[3] *= bf2f(g4.w);
  float s1 = ov[0] + ov[1] + ov[2] + ov[3];
  float s2 = ov[0]*ov[0] + ov[1]*ov[1] + ov[2]*ov[2] + ov[3]*ov[3];
#pragma unroll
  for (int off = 1; off < 64; off <<= 1){ s1 += __shfl_xor(s1, off); s2 += __shfl_xor(s2, off); }
  __shared__ float w1[4], w2[4];
  const int w = tid >> 6;
  if ((tid & 63) == 0){ w1[w] = s1; w2[w] = s2; }
  __syncthreads();
  s1 = w1[0] + w1[1] + w1[2] + w1[3];
  s2 = w2[0] + w2[1] + w2[2] + w2[3];
  const float mu  = s1 * (1.0f/1024.0f);
  const float var = s2 * (1.0f/1024.0f) - mu*mu;
  const float rs  = rsqrtf(var + 1e-5f);
  const float4 n4 = *(const float4*)(nw + tid * 4);
  ushort4 ou;
  ou.x = f2bf((ov[0] - mu) * rs * n4.x);
  ou.y = f2bf((ov[1] - mu) * rs * n4.y);
  ou.z = f2bf((ov[2] - mu) * rs * n4.z);
  ou.w = f2bf((ov[3] - mu) * rs * n4.w);
  *(ushort4*)(onb + base) = ou;
}

// ---------------- launcher ----------------
extern "C" void kernel_launch(void* const* d_in, const int* in_sizes, int n_in,
                              void* d_out, int out_size, void* d_ws, size_t ws_size,
                              hipStream_t stream){
  const float* x    = (const float*)d_in[0];
  const float* Wq   = (const float*)d_in[1];
  const float* Wk   = (const float*)d_in[2];
  const float* Wv   = (const float*)d_in[3];
  const float* Wg   = (const float*)d_in[4];
  const float* Wf1  = (const float*)d_in[5];
  const float* Wf2  = (const float*)d_in[6];
  const float* Wog1 = (const float*)d_in[7];
  const float* Wog2 = (const float*)d_in[8];
  const float* nw   = (const float*)d_in[9];
  const float* Wo   = (const float*)d_in[10];

  // workspace budget check (bail cleanly instead of faulting)
  if (ws_size < 97779712ull) return;

  char* base = (char*)d_ws;
  size_t off = 0;
  auto alloc = [&](size_t bytes)->char*{
    char* r = base + off; off += (bytes + 255) & ~(size_t)255; return r;
  };
  unsigned short* xb    = (unsigned short*)alloc((size_t)M_*D_*2);      // 16MB (scan out reuses)
  unsigned short* WqT   = (unsigned short*)alloc((size_t)D_*D_*2);      // 2MB
  unsigned short* WkT   = (unsigned short*)alloc((size_t)D_*D_*2);
  unsigned short* WvT   = (unsigned short*)alloc((size_t)D_*D_*2);
  unsigned short* WoT   = (unsigned short*)alloc((size_t)D_*D_*2);
  unsigned short* WgfoT = (unsigned short*)alloc((size_t)256*D_*2);     // 0.5MB
  unsigned short* Wf2T  = (unsigned short*)alloc((size_t)D_*64*2);      // 128KB
  unsigned short* Wog2T = (unsigned short*)alloc((size_t)D_*64*2);
  unsigned short* qb    = (unsigned short*)alloc((size_t)M_*D_*2);      // 16MB (og-sig reuses)
  unsigned short* kb    = (unsigned short*)alloc((size_t)M_*D_*2);      // 16MB (LN out reuses)
  unsigned short* vb    = (unsigned short*)alloc((size_t)M_*D_*2);      // 16MB
  unsigned short* gfo   = (unsigned short*)alloc((size_t)M_*256*2);     // 4MB
  unsigned short* efb   = (unsigned short*)alloc((size_t)M_*D_*2);      // 16MB
  float*          gammac= (float*)alloc((size_t)64*T_*4);               // 0.5MB
  // aliases (strictly ordered reuse):
  unsigned short* obuf = xb;   // xb dead after level-1 GEMMs; scan writes here
  unsigned short* ogs  = qb;   // qb dead after scan; og-sigmoid GEMM writes here
  unsigned short* onb  = kb;   // kb dead after scan; gate_ln writes here

  dim3 blkT(32, 8);

  // converts / transposes
  k_f32_to_bf16<<<8192, 256, 0, stream>>>(x, xb, M_*D_);
  k_transpose_bf16<<<dim3(32,32), blkT, 0, stream>>>(Wq,   WqT,  1024, 1024, 1024);
  k_transpose_bf16<<<dim3(32,32), blkT, 0, stream>>>(Wk,   WkT,  1024, 1024, 1024);
  k_transpose_bf16<<<dim3(32,32), blkT, 0, stream>>>(Wv,   WvT,  1024, 1024, 1024);
  k_transpose_bf16<<<dim3(32,32), blkT, 0, stream>>>(Wo,   WoT,  1024, 1024, 1024);
  // fused bottleneck weights: rows 0-15 Wg^T, 16-79 Wf1^T, 80-143 Wog1^T, 144-255 zero
  k_transpose_bf16<<<dim3(32,1),  blkT, 0, stream>>>(Wg,   WgfoT,            1024, 16,  16);
  k_transpose_bf16<<<dim3(32,2),  blkT, 0, stream>>>(Wf1,  WgfoT + 16*1024,  1024, 64,  64);
  k_transpose_bf16<<<dim3(32,6),  blkT, 0, stream>>>(Wog1, WgfoT + 80*1024,  1024, 64, 176);
  k_transpose_bf16<<<dim3(2,32),  blkT, 0, stream>>>(Wf2,  Wf2T,  64, 1024, 1024);
  k_transpose_bf16<<<dim3(2,32),  blkT, 0, stream>>>(Wog2, Wog2T, 64, 1024, 1024);

  // level-1 projections with fused activations
  k_gemm<2><<<dim3(8,64), 256, 0, stream>>>(xb, WqT,   qb,  1024, 1024, 1024, nullptr); // silu
  k_gemm<4><<<dim3(8,64), 256, 0, stream>>>(xb, WkT,   kb,  1024, 1024, 1024, nullptr); // silu+l2norm
  k_gemm<1><<<dim3(8,64), 256, 0, stream>>>(xb, WvT,   vb,  1024, 1024, 1024, nullptr); // plain
  k_gemm<5><<<dim3(2,64), 256, 0, stream>>>(xb, WgfoT, gfo, 1024, 1024, 256,  gammac); // + gamma
  // level-2 bottleneck GEMM: ef = sigmoid(fmid @ Wf2)
  k_gemm<3><<<dim3(8,64), 256, 0, stream>>>(gfo + 16, Wf2T, efb, 64, 256, 1024, nullptr);

  // sequential recurrence (writes obuf = xb)
  k_scan<<<1024, 64, 0, stream>>>(qb, kb, vb, efb, gammac, obuf);

  // og gate: sigmoid(ogmid @ Wog2) -> ogs (= qb, dead after scan)
  k_gemm<3><<<dim3(8,64), 256, 0, stream>>>(gfo + 80, Wog2T, ogs, 64, 256, 1024, nullptr);

  // gate + layernorm (writes onb = kb)
  k_gate_ln<<<8192, 256, 0, stream>>>(obuf, ogs, nw, onb);

  // final projection -> d_out (fp32)
  k_gemm<0><<<dim3(8,64), 256, 0, stream>>>(onb, WoT, (float*)d_out, 1024, 1024, 1024, nullptr);
}